// Round 13
// baseline (647.119 us; speedup 1.0000x reference)
//
#include <hip/hip_runtime.h>
#include <hip/hip_bf16.h>

typedef unsigned short u16;
typedef __attribute__((ext_vector_type(8))) short short8;
typedef __attribute__((ext_vector_type(4))) short short4v;
typedef __attribute__((ext_vector_type(4))) float f32x4;

#define NN 50000
#define EE 400000
#define GG 256
#define MP 50048      // 391 * 128 padded rows
#define KS 64         // gemm1 K: 23 node_s + 16 vnorm + 1 ones + 24 zero
#define K2 320        // gemm2 K: 40 + 256 meanH + 24 zero

static __device__ __forceinline__ __hip_bfloat16 f2b(float x) { return __float2bfloat16(x); }
static __device__ __forceinline__ float u16tof(u16 v) {
    unsigned x = ((unsigned)v) << 16;
    float f;
    __builtin_memcpy(&f, &x, 4);
    return f;
}
static __device__ __forceinline__ u16 ftou16(float x) {
    __hip_bfloat16 h = __float2bfloat16(x);
    u16 b;
    __builtin_memcpy(&b, &h, 2);
    return b;
}
static __device__ __forceinline__ void st_out(float* p, float v) { *p = v; }
static __device__ __forceinline__ void st_out(__hip_bfloat16* p, float v) { *p = f2b(v); }

// uniform row a[j] (scalar loads) dotted with column b[j*256+c] (coalesced), 4-way split chain
static __device__ __forceinline__ float dot256(const float* __restrict__ a,
                                               const float* __restrict__ b, int c) {
    float a0 = 0.f, a1 = 0.f, a2 = 0.f, a3 = 0.f;
    for (int j = 0; j < 256; j += 4) {
        a0 += a[j]     * b[(size_t)j * 256 + c];
        a1 += a[j + 1] * b[(size_t)(j + 1) * 256 + c];
        a2 += a[j + 2] * b[(size_t)(j + 2) * 256 + c];
        a3 += a[j + 3] * b[(size_t)(j + 3) * 256 + c];
    }
    return (a0 + a1) + (a2 + a3);
}

// ================= phase1: coalesced packing + embed-lite + degree counts =================
__global__ __launch_bounds__(256) void phase1(const float* __restrict__ Wm1,
                                              const float* __restrict__ Wn,
                                              const float* __restrict__ Wm2,
                                              const float* __restrict__ We,
                                              const float* __restrict__ be,
                                              const float* __restrict__ bm1,
                                              const float* __restrict__ bm2,
                                              const float* __restrict__ Ws,
                                              const float* __restrict__ bs,
                                              __hip_bfloat16* __restrict__ W1pqT,
                                              __hip_bfloat16* __restrict__ W2T,
                                              float* __restrict__ Wc, float* __restrict__ bc,
                                              float* __restrict__ crow,
                                              const float* __restrict__ node_s,
                                              const float* __restrict__ node_v,
                                              const float* __restrict__ Wv,
                                              const float* __restrict__ bv,
                                              __hip_bfloat16* __restrict__ XL2,
                                              const int* __restrict__ ei,
                                              const int* __restrict__ batch,
                                              int* __restrict__ cnt, int* __restrict__ gcnt) {
    int blk = blockIdx.x, tid = threadIdx.x;
    if (blk < 64) {
        int k = blk;
#pragma unroll
        for (int half = 0; half < 2; ++half) {
            int c = half * 256 + tid;
            int cc = c & 255;
            const float* Wm1h = (c < 256) ? Wm1 : (Wm1 + 256 * 256);
            float v = 0.f;
            if (k < 23) v = dot256(&Ws[k * 256], Wm1h, cc);
            else if (k < 39) { if (c >= 256) v = Wm1[(512 + (k - 23)) * 256 + cc]; }
            else if (k == 39) v = dot256(bs, Wm1h, cc);
            W1pqT[c * KS + k] = f2b(v);
        }
    } else if (blk < 384) {
        int k = blk - 64, c = tid;
        float v = 0.f;
        if (k < 23) v = dot256(&Ws[k * 256], Wn, c);
        else if (k < 39) v = Wn[(256 + (k - 23)) * 256 + c];
        else if (k == 39) v = dot256(bs, Wn, c);
        else if (k < 296) v = dot256(&Wm2[(k - 40) * 256], Wn, c);
        W2T[c * K2 + k] = f2b(v);
    } else if (blk < 403) {
        int b = blk - 384, c = tid;
        if (b < 17) Wc[b * 256 + c] = dot256(&We[b * 256], &Wm1[528 * 256], c);
        else if (b == 17) bc[c] = bm1[c] + dot256(be, &Wm1[528 * 256], c);
        else crow[c] = dot256(bm2, Wn, c);
    } else if (blk < 12903) {
        int w = tid >> 6, lane = tid & 63;
        int n = (blk - 403) * 4 + w;
        if (n < NN) {
            float lv = (lane < 23) ? node_s[(size_t)n * 23 + lane] : 0.f;
            float vv = (lane < 12) ? node_v[(size_t)n * 12 + lane] : 0.f;
            float nvk[12];
#pragma unroll
            for (int k = 0; k < 12; ++k) nvk[k] = __shfl(vv, k, 64);
            float vn = 0.f;
            if (lane < 16) {
                float b0 = bv[lane];
                float vx = b0, vy = b0, vz = b0;
#pragma unroll
                for (int k = 0; k < 4; ++k) {
                    float wv = Wv[k * 16 + lane];
                    vx += nvk[k * 3 + 0] * wv;
                    vy += nvk[k * 3 + 1] * wv;
                    vz += nvk[k * 3 + 2] * wv;
                }
                vn = sqrtf(vx * vx + vy * vy + vz * vz);
            }
            int vsrc = (lane >= 23 && lane < 39) ? (lane - 23) : 0;
            float vbc = __shfl(vn, vsrc, 64);
            float outv;
            if (lane < 23) outv = lv;
            else if (lane < 39) outv = vbc;
            else if (lane == 39) outv = 1.f;
            else outv = 0.f;
            __hip_bfloat16* row = XL2 + (size_t)n * K2;
            row[lane] = f2b(outv);
            if (lane < 24) row[296 + lane] = f2b(0.f);
        }
    } else {
        int b = blk - 12903;
        if (b < 1563) {
            int e = b * 256 + tid;
            if (e < EE) atomicAdd(&cnt[ei[EE + e]], 1);
        } else {
            int n = (b - 1563) * 256 + tid;
            if (n < NN) atomicAdd(&gcnt[batch[n]], 1);
        }
    }
}

// ================= CSR build =================
__global__ __launch_bounds__(256) void scan1(const int* __restrict__ cnt, int* __restrict__ rowptr,
                                             int* __restrict__ bsum) {
    int tid = threadIdx.x, i = blockIdx.x * 256 + tid;
    __shared__ int sd[256];
    int v = (i < NN) ? cnt[i] : 0;
    sd[tid] = v;
    __syncthreads();
    for (int off = 1; off < 256; off <<= 1) {
        int t = (tid >= off) ? sd[tid - off] : 0;
        __syncthreads();
        sd[tid] += t;
        __syncthreads();
    }
    if (i < NN) rowptr[i] = sd[tid] - v;
    if (tid == 255) bsum[blockIdx.x] = sd[255];
}
__global__ __launch_bounds__(256) void scan2(int* __restrict__ bsum, const int* __restrict__ gcnt,
                                             float* __restrict__ ginv) {
    int c = threadIdx.x;
    __shared__ int sd[256];
    int v = (c < 196) ? bsum[c] : 0;
    sd[c] = v;
    __syncthreads();
    for (int off = 1; off < 256; off <<= 1) {
        int t = (c >= off) ? sd[c - off] : 0;
        __syncthreads();
        sd[c] += t;
        __syncthreads();
    }
    if (c < 196) bsum[c] = sd[c] - v;
    ginv[c] = 1.f / fmaxf((float)gcnt[c], 1.f);
}
__global__ __launch_bounds__(256) void scan3(const int* __restrict__ cnt, const int* __restrict__ bsum,
                                             int* __restrict__ rowptr, int* __restrict__ cursor) {
    int i = blockIdx.x * 256 + threadIdx.x;
    if (i < NN) {
        int v = rowptr[i] + bsum[blockIdx.x];
        rowptr[i] = v;
        cursor[i] = v;
        if (i == NN - 1) rowptr[NN] = v + cnt[i];
    }
}
__global__ __launch_bounds__(256) void fill_csr(const int* __restrict__ ei, int* __restrict__ cursor,
                                                int* __restrict__ eid, int* __restrict__ dstv) {
    int e = blockIdx.x * 256 + threadIdx.x;
    if (e < EE) {
        int d = ei[EE + e];
        int pos = atomicAdd(&cursor[d], 1);
        eid[pos] = e;
        dstv[pos] = d;
    }
}

// ================= MFMA GEMM (gemm1): C[M x Ncols] = A[M x K] * Bt[Ncols x K]^T =================
template <typename OutT>
__global__ __launch_bounds__(256, 2) void gemm_bt(const u16* __restrict__ A, const u16* __restrict__ Bt,
                                                  OutT* __restrict__ C, int K, int lda, int Ncols) {
    __shared__ __align__(16) u16 At[128 * 64];
    __shared__ __align__(16) u16 Bs[128 * 64];
    int tid = threadIdx.x;
    long m0 = (long)blockIdx.x * 128;
    long n0 = (long)blockIdx.y * 128;
    int wid = tid >> 6, lane = tid & 63;
    int wm = wid >> 1, wn = wid & 1;
    int quad = lane >> 4, l16 = lane & 15;
    f32x4 acc[4][4] = {};
    int r0 = tid >> 3;
    int cc = (tid & 7) * 8;
    const u16* Ab = A + (m0 + r0) * lda + cc;
    const u16* Bb = Bt + (n0 + r0) * K + cc;
    for (int kt = 0; kt < K; kt += 64) {
#pragma unroll
        for (int i = 0; i < 4; ++i) {
            int row = r0 + i * 32;
            __builtin_amdgcn_global_load_lds(
                (const __attribute__((address_space(1))) void*)(Ab + (long)(i * 32) * lda + kt),
                (__attribute__((address_space(3))) void*)(&At[row * 64 + cc]), 16, 0, 0);
        }
#pragma unroll
        for (int i = 0; i < 4; ++i) {
            int row = r0 + i * 32;
            __builtin_amdgcn_global_load_lds(
                (const __attribute__((address_space(1))) void*)(Bb + (long)(i * 32) * K + kt),
                (__attribute__((address_space(3))) void*)(&Bs[row * 64 + cc]), 16, 0, 0);
        }
        __syncthreads();
#pragma unroll
        for (int kk = 0; kk < 64; kk += 32) {
            short8 af[4], bf[4];
#pragma unroll
            for (int mi = 0; mi < 4; ++mi)
                af[mi] = *(const short8*)&At[(wm * 64 + mi * 16 + l16) * 64 + kk + quad * 8];
#pragma unroll
            for (int ni = 0; ni < 4; ++ni)
                bf[ni] = *(const short8*)&Bs[(wn * 64 + ni * 16 + l16) * 64 + kk + quad * 8];
#pragma unroll
            for (int mi = 0; mi < 4; ++mi) {
#pragma unroll
                for (int ni = 0; ni < 4; ++ni)
                    acc[mi][ni] = __builtin_amdgcn_mfma_f32_16x16x32_bf16(af[mi], bf[ni], acc[mi][ni], 0, 0, 0);
            }
        }
        __syncthreads();
    }
#pragma unroll
    for (int mi = 0; mi < 4; ++mi) {
#pragma unroll
        for (int ni = 0; ni < 4; ++ni) {
            long row = m0 + wm * 64 + mi * 16 + quad * 4;
            long col = n0 + wn * 64 + ni * 16 + l16;
#pragma unroll
            for (int r = 0; r < 4; ++r)
                st_out(&C[(row + r) * Ncols + col], acc[mi][ni][r]);
        }
    }
}

// ================= FAST PATH a: edge_ma — 8 CSR positions per wave, NO serial chain ==============
// m_e = relu(P[dst]+bc + Q[src] + edge_s[e]@Wc); per-wave run-length grouping by dst (CSR is
// dst-sorted) -> f32 atomicAdd flush per run into meanHf32. All gather addresses staged up
// front, so q/p/es loads are independent -> MLP hides latency (the R5-R11 serial chain is gone).
__global__ __launch_bounds__(256, 1) void edge_ma(const u16* __restrict__ PQ,
                                                  const float* __restrict__ edge_s,
                                                  const int* __restrict__ ei, const int* __restrict__ eid,
                                                  const int* __restrict__ dstv,
                                                  const float* __restrict__ Wc, const float* __restrict__ bc,
                                                  float* __restrict__ meanHf32) {
    int w = threadIdx.x >> 6, lane = threadIdx.x & 63;
    int base = (blockIdx.x * 4 + w) * 8;          // 50000 waves x 8 = EE exactly
    if (base >= EE) return;
    f32x4 wc4[17];
#pragma unroll
    for (int k = 0; k < 17; ++k) wc4[k] = *(const f32x4*)&Wc[k * 256 + lane * 4];
    f32x4 bc4 = *(const f32x4*)&bc[lane * 4];
    int eL = 0, dL = 0, sL = 0;
    if (lane < 8) {
        eL = eid[base + lane];
        dL = dstv[base + lane];
        sL = ei[eL];
    }
    f32x4 acc = {0.f, 0.f, 0.f, 0.f};
    int dprev = __shfl(dL, 0);
#pragma unroll 4
    for (int u = 0; u < 8; ++u) {
        int e = __shfl(eL, u), d = __shfl(dL, u), s = __shfl(sL, u);
        short4v q4 = *(const short4v*)&PQ[(size_t)s * 512 + 256 + lane * 4];
        short4v p4 = *(const short4v*)&PQ[(size_t)d * 512 + lane * 4];
        float esv = (lane < 17) ? edge_s[(size_t)e * 17 + lane] : 0.f;
        if (d != dprev) {   // wave-uniform
#pragma unroll
            for (int i = 0; i < 4; ++i) atomicAdd(&meanHf32[(size_t)dprev * 256 + lane * 4 + i], acc[i]);
            acc = {0.f, 0.f, 0.f, 0.f};
            dprev = d;
        }
        f32x4 ra = bc4;
        f32x4 rb = {0.f, 0.f, 0.f, 0.f};
#pragma unroll
        for (int k = 0; k < 8; ++k) ra += wc4[k] * __shfl(esv, k);
#pragma unroll
        for (int k = 8; k < 17; ++k) rb += wc4[k] * __shfl(esv, k);
#pragma unroll
        for (int i = 0; i < 4; ++i)
            acc[i] += fmaxf(ra[i] + rb[i] + u16tof((u16)p4[i]) + u16tof((u16)q4[i]), 0.f);
    }
#pragma unroll
    for (int i = 0; i < 4; ++i) atomicAdd(&meanHf32[(size_t)dprev * 256 + lane * 4 + i], acc[i]);
}

// ================= FAST PATH b: mean_fin — divide by deg, write bf16 meanH into XL2 ==============
__global__ __launch_bounds__(256, 1) void mean_fin(const float* __restrict__ meanHf32,
                                                   const int* __restrict__ cnt,
                                                   __hip_bfloat16* __restrict__ XL2) {
    int w = threadIdx.x >> 6, lane = threadIdx.x & 63;
    int n = blockIdx.x * 4 + w;
    if (n >= NN) return;
    float inv = 1.f / fmaxf((float)cnt[n], 1.f);
    f32x4 v = *(const f32x4*)&meanHf32[(size_t)n * 256 + lane * 4];
    short4v ov;
#pragma unroll
    for (int i = 0; i < 4; ++i) ov[i] = (short)ftou16(v[i] * inv);
    *(short4v*)&XL2[(size_t)n * K2 + 40 + lane * 4] = ov;
}

// ================= FALLBACK: R9-verified edge_agg (if ws too small for meanHf32) ==============
__global__ __launch_bounds__(256, 1) void edge_agg(const u16* __restrict__ PQ,
                                                   const float* __restrict__ edge_s,
                                                   const int* __restrict__ ei, const int* __restrict__ eid,
                                                   const int* __restrict__ rowptr, const float* __restrict__ Wc,
                                                   const float* __restrict__ bc, __hip_bfloat16* __restrict__ XL2) {
    int w = threadIdx.x >> 6, lane = threadIdx.x & 63;
    int n = blockIdx.x * 4 + w;
    if (n >= NN) return;
    int start = rowptr[n], deg = rowptr[n + 1] - start;
    f32x4 wc4[17];
#pragma unroll
    for (int k = 0; k < 17; ++k) wc4[k] = *(const f32x4*)&Wc[k * 256 + lane * 4];
    f32x4 bc4 = *(const f32x4*)&bc[lane * 4];
    short4v p4 = *(const short4v*)&PQ[(size_t)n * 512 + lane * 4];
    f32x4 pb;
#pragma unroll
    for (int i = 0; i < 4; ++i) pb[i] = u16tof((u16)p4[i]) + bc4[i];
    f32x4 acc = {0.f, 0.f, 0.f, 0.f};
    for (int base = 0; base < deg; base += 64) {
        int m = deg - base;
        if (m > 64) m = 64;
        int ee = 0, ss = 0;
        if (lane < m) {
            ee = eid[start + base + lane];
            ss = ei[ee];
        }
        int e0 = __shfl(ee, 0), s0 = __shfl(ss, 0);
        short4v q0 = *(const short4v*)&PQ[(size_t)s0 * 512 + 256 + lane * 4];
        float es0 = (lane < 17) ? edge_s[(size_t)e0 * 17 + lane] : 0.f;
        for (int jj = 0; jj < m; ++jj) {
            short4v q1 = q0;
            float es1 = es0;
            if (jj + 1 < m) {
                int e1 = __shfl(ee, jj + 1), s1 = __shfl(ss, jj + 1);
                q1 = *(const short4v*)&PQ[(size_t)s1 * 512 + 256 + lane * 4];
                es1 = (lane < 17) ? edge_s[(size_t)e1 * 17 + lane] : 0.f;
            }
            f32x4 ra = {0.f, 0.f, 0.f, 0.f};
            f32x4 rb = {0.f, 0.f, 0.f, 0.f};
#pragma unroll
            for (int k = 0; k < 8; ++k) ra += wc4[k] * __shfl(es0, k);
#pragma unroll
            for (int k = 8; k < 17; ++k) rb += wc4[k] * __shfl(es0, k);
#pragma unroll
            for (int i = 0; i < 4; ++i)
                acc[i] += fmaxf(pb[i] + u16tof((u16)q0[i]) + ra[i] + rb[i], 0.f);
            q0 = q1;
            es0 = es1;
        }
    }
    float inv = 1.f / fmaxf((float)deg, 1.f);
    short4v ov;
#pragma unroll
    for (int i = 0; i < 4; ++i) ov[i] = (short)ftou16(acc[i] * inv);
    *(short4v*)&XL2[(size_t)n * K2 + 40 + lane * 4] = ov;
}

// ================= gemm2 + LayerNorm + ReLU + pool, fully fused =================
__global__ __launch_bounds__(256, 2) void gemm2_lnp(const u16* __restrict__ A, const u16* __restrict__ Bt,
                                                    const int* __restrict__ cnt, const int* __restrict__ batch,
                                                    const float* __restrict__ bn, const float* __restrict__ crow,
                                                    const float* __restrict__ gamma, const float* __restrict__ beta,
                                                    const float* __restrict__ ginv, float* __restrict__ out) {
    __shared__ __align__(16) u16 At[64 * 64];
    __shared__ __align__(16) u16 Bs[256 * 64];
    __shared__ float rsum[4][64], rsum2[4][64];
    __shared__ int sdeg[64], sbatch[64];
    int tid = threadIdx.x;
    long m0 = (long)blockIdx.x * 64;
    int w = tid >> 6, lane = tid & 63;
    int quad = lane >> 4, l16 = lane & 15;
    f32x4 acc[4][4] = {};
    int r0 = tid >> 3;
    int cc = (tid & 7) * 8;
    const u16* Ab = A + (m0 + r0) * K2 + cc;
    const u16* Bb = Bt + (long)r0 * K2 + cc;
    for (int kt = 0; kt < K2; kt += 64) {
#pragma unroll
        for (int i = 0; i < 2; ++i) {
            int row = r0 + i * 32;
            __builtin_amdgcn_global_load_lds(
                (const __attribute__((address_space(1))) void*)(Ab + (long)(i * 32) * K2 + kt),
                (__attribute__((address_space(3))) void*)(&At[row * 64 + cc]), 16, 0, 0);
        }
#pragma unroll
        for (int i = 0; i < 8; ++i) {
            int row = r0 + i * 32;
            __builtin_amdgcn_global_load_lds(
                (const __attribute__((address_space(1))) void*)(Bb + (long)(i * 32) * K2 + kt),
                (__attribute__((address_space(3))) void*)(&Bs[row * 64 + cc]), 16, 0, 0);
        }
        __syncthreads();
#pragma unroll
        for (int kk = 0; kk < 64; kk += 32) {
            short8 af[4], bf[4];
#pragma unroll
            for (int mi = 0; mi < 4; ++mi)
                af[mi] = *(const short8*)&At[(mi * 16 + l16) * 64 + kk + quad * 8];
#pragma unroll
            for (int ni = 0; ni < 4; ++ni)
                bf[ni] = *(const short8*)&Bs[(w * 64 + ni * 16 + l16) * 64 + kk + quad * 8];
#pragma unroll
            for (int mi = 0; mi < 4; ++mi) {
#pragma unroll
                for (int ni = 0; ni < 4; ++ni)
                    acc[mi][ni] = __builtin_amdgcn_mfma_f32_16x16x32_bf16(af[mi], bf[ni], acc[mi][ni], 0, 0, 0);
            }
        }
        __syncthreads();
    }
    if (tid < 64) {
        long n = m0 + tid;
        sdeg[tid] = (n < NN) ? cnt[n] : 0;
        sbatch[tid] = (n < NN) ? batch[n] : -1;
    }
    __syncthreads();
    float bn_l[4], cr_l[4], g_l[4], be_l[4];
#pragma unroll
    for (int ni = 0; ni < 4; ++ni) {
        int col = w * 64 + ni * 16 + l16;
        bn_l[ni] = bn[col];
        cr_l[ni] = crow[col];
        g_l[ni] = gamma[col];
        be_l[ni] = beta[col];
    }
#pragma unroll
    for (int mi = 0; mi < 4; ++mi) {
#pragma unroll
        for (int r = 0; r < 4; ++r) {
            int row = mi * 16 + quad * 4 + r;
            float cr_on = (sdeg[row] > 0) ? 1.f : 0.f;
            float s = 0.f, s2 = 0.f;
#pragma unroll
            for (int ni = 0; ni < 4; ++ni) {
                float xv = acc[mi][ni][r] + bn_l[ni] + cr_on * cr_l[ni];
                acc[mi][ni][r] = xv;
                s += xv;
                s2 += xv * xv;
            }
            s += __shfl_xor(s, 1, 64);  s2 += __shfl_xor(s2, 1, 64);
            s += __shfl_xor(s, 2, 64);  s2 += __shfl_xor(s2, 2, 64);
            s += __shfl_xor(s, 4, 64);  s2 += __shfl_xor(s2, 4, 64);
            s += __shfl_xor(s, 8, 64);  s2 += __shfl_xor(s2, 8, 64);
            if (l16 == 0) { rsum[w][row] = s; rsum2[w][row] = s2; }
        }
    }
    __syncthreads();
    float mu_a[4][4], rs_a[4][4];
#pragma unroll
    for (int mi = 0; mi < 4; ++mi) {
#pragma unroll
        for (int r = 0; r < 4; ++r) {
            int row = mi * 16 + quad * 4 + r;
            float S = rsum[0][row] + rsum[1][row] + rsum[2][row] + rsum[3][row];
            float S2 = rsum2[0][row] + rsum2[1][row] + rsum2[2][row] + rsum2[3][row];
            float mu = S * (1.f / 256.f);
            mu_a[mi][r] = mu;
            rs_a[mi][r] = rsqrtf(S2 * (1.f / 256.f) - mu * mu + 1e-5f);
        }
    }
#pragma unroll
    for (int ni = 0; ni < 4; ++ni) {
        int col = w * 64 + ni * 16 + l16;
        float pacc = 0.f;
        int curg = -1;
#pragma unroll
        for (int mi = 0; mi < 4; ++mi) {
#pragma unroll
            for (int r = 0; r < 4; ++r) {
                int row = mi * 16 + quad * 4 + r;
                int g = sbatch[row];
                float y = (acc[mi][ni][r] - mu_a[mi][r]) * rs_a[mi][r] * g_l[ni] + be_l[ni];
                y = fmaxf(y, 0.f);
                if (g != curg) {
                    if (curg >= 0) atomicAdd(&out[curg * 256 + col], pacc * ginv[curg]);
                    pacc = 0.f;
                    curg = g;
                }
                if (g >= 0) pacc += y;
            }
        }
        if (curg >= 0) atomicAdd(&out[curg * 256 + col], pacc * ginv[curg]);
    }
}

extern "C" void kernel_launch(void* const* d_in, const int* in_sizes, int n_in,
                              void* d_out, int out_size, void* d_ws, size_t ws_size,
                              hipStream_t stream) {
    const float* node_s = (const float*)d_in[0];
    const float* node_v = (const float*)d_in[1];
    const float* edge_s = (const float*)d_in[2];
    const int* ei = (const int*)d_in[3];
    const int* batch = (const int*)d_in[4];
    const float* Ws = (const float*)d_in[5];
    const float* bs = (const float*)d_in[6];
    const float* Wv = (const float*)d_in[7];
    const float* bv = (const float*)d_in[8];
    const float* We = (const float*)d_in[9];
    const float* be = (const float*)d_in[10];
    const float* Wm1 = (const float*)d_in[11];
    const float* bm1 = (const float*)d_in[12];
    const float* Wm2 = (const float*)d_in[13];
    const float* bm2 = (const float*)d_in[14];
    const float* Wn = (const float*)d_in[15];
    const float* bn = (const float*)d_in[16];
    const float* gamma = (const float*)d_in[17];
    const float* beta = (const float*)d_in[18];

    char* ws = (char*)d_ws;
    size_t off = 0;
    auto take = [&](size_t n) {
        void* p = ws + off;
        off = (off + n + 255) & ~(size_t)255;
        return p;
    };
    __hip_bfloat16* XL2 = (__hip_bfloat16*)take((size_t)MP * K2 * 2);
    __hip_bfloat16* PQ = (__hip_bfloat16*)take((size_t)MP * 512 * 2);
    __hip_bfloat16* W1pqT = (__hip_bfloat16*)take(512 * KS * 2);
    __hip_bfloat16* W2T = (__hip_bfloat16*)take(256 * K2 * 2);
    float* Wc = (float*)take(17 * 256 * 4);
    float* bc = (float*)take(256 * 4);
    float* crow = (float*)take(256 * 4);
    int* cnt = (int*)take((NN + GG) * 4);
    int* gcnt = cnt + NN;
    float* ginv = (float*)take(GG * 4);
    int* rowptr = (int*)take((NN + 1) * 4);
    int* cursor = (int*)take(NN * 4);
    int* eid = (int*)take(EE * 4);
    int* dstv = (int*)take(EE * 4);
    int* bsum = (int*)take(256 * 4);
    // meanHf32 last: fast path only if the workspace can hold it (51.2 MB)
    size_t mh_bytes = (size_t)MP * 256 * 4;
    bool fast = (off + mh_bytes + 256) <= ws_size;
    float* meanHf32 = fast ? (float*)take(mh_bytes) : nullptr;

    hipMemsetAsync(cnt, 0, (NN + GG) * 4, stream);
    hipMemsetAsync(d_out, 0, (size_t)out_size * 4, stream);
    if (fast) hipMemsetAsync(meanHf32, 0, (size_t)NN * 256 * 4, stream);

    phase1<<<14662, 256, 0, stream>>>(Wm1, Wn, Wm2, We, be, bm1, bm2, Ws, bs,
                                      W1pqT, W2T, Wc, bc, crow,
                                      node_s, node_v, Wv, bv, XL2, ei, batch, cnt, gcnt);

    scan1<<<196, 256, 0, stream>>>(cnt, rowptr, bsum);
    scan2<<<1, 256, 0, stream>>>(bsum, gcnt, ginv);
    scan3<<<196, 256, 0, stream>>>(cnt, bsum, rowptr, cursor);
    fill_csr<<<(EE + 255) / 256, 256, 0, stream>>>(ei, cursor, eid, dstv);

    // PQ = XL2[:, :64] @ W1pqT^T   (K=64, lda=320, Ncols=512), bf16 out
    gemm_bt<__hip_bfloat16><<<dim3(391, 4), 256, 0, stream>>>((const u16*)XL2, (const u16*)W1pqT, PQ, KS, K2, 512);

    if (fast) {
        edge_ma<<<12500, 256, 0, stream>>>((const u16*)PQ, edge_s, ei, eid, dstv, Wc, bc, meanHf32);
        mean_fin<<<12512, 256, 0, stream>>>(meanHf32, cnt, XL2);
    } else {
        edge_agg<<<12500, 256, 0, stream>>>((const u16*)PQ, edge_s, ei, eid, rowptr, Wc, bc, XL2);
    }

    // fused: h = XL2 @ W2T^T -> LN -> ReLU -> mean-pool into d_out
    gemm2_lnp<<<782, 256, 0, stream>>>((const u16*)XL2, (const u16*)W2T, cnt, batch,
                                       bn, crow, gamma, beta, ginv, (float*)d_out);
}

// Round 14
// 375.306 us; speedup vs baseline: 1.7242x; 1.7242x over previous
//
#include <hip/hip_runtime.h>
#include <hip/hip_bf16.h>

typedef unsigned short u16;
typedef __attribute__((ext_vector_type(8))) short short8;
typedef __attribute__((ext_vector_type(4))) short short4v;
typedef __attribute__((ext_vector_type(4))) float f32x4;

#define NN 50000
#define EE 400000
#define GG 256
#define MP 50048      // 391 * 128 padded rows
#define KS 64         // gemm1 K: 23 node_s + 16 vnorm + 1 ones + 24 zero
#define K2 320        // gemm2 K: 40 + 256 meanH + 24 zero
#define ESN (EE * 17) // edge_s elements

static __device__ __forceinline__ __hip_bfloat16 f2b(float x) { return __float2bfloat16(x); }
static __device__ __forceinline__ float u16tof(u16 v) {
    unsigned x = ((unsigned)v) << 16;
    float f;
    __builtin_memcpy(&f, &x, 4);
    return f;
}
static __device__ __forceinline__ u16 ftou16(float x) {
    __hip_bfloat16 h = __float2bfloat16(x);
    u16 b;
    __builtin_memcpy(&b, &h, 2);
    return b;
}
static __device__ __forceinline__ float rlf(float v, int l) {
    unsigned u;
    __builtin_memcpy(&u, &v, 4);
    unsigned r = (unsigned)__builtin_amdgcn_readlane((int)u, l);
    float f;
    __builtin_memcpy(&f, &r, 4);
    return f;
}
static __device__ __forceinline__ void st_out(float* p, float v) { *p = v; }
static __device__ __forceinline__ void st_out(__hip_bfloat16* p, float v) { *p = f2b(v); }

// uniform row a[j] (scalar loads) dotted with column b[j*256+c] (coalesced), 4-way split chain
static __device__ __forceinline__ float dot256(const float* __restrict__ a,
                                               const float* __restrict__ b, int c) {
    float a0 = 0.f, a1 = 0.f, a2 = 0.f, a3 = 0.f;
    for (int j = 0; j < 256; j += 4) {
        a0 += a[j]     * b[(size_t)j * 256 + c];
        a1 += a[j + 1] * b[(size_t)(j + 1) * 256 + c];
        a2 += a[j + 2] * b[(size_t)(j + 2) * 256 + c];
        a3 += a[j + 3] * b[(size_t)(j + 3) * 256 + c];
    }
    return (a0 + a1) + (a2 + a3);
}

// ================= phase1: packing + embed-lite + degree counts + edge_s->bf16 staging =========
// blocks [0,64): W1pqT   [64,384): W2T   [384,403): Wc/bc/crow
// [403,12903): embed-lite   [12903,14662): degree counts   [14662,41225): esb conversion
__global__ __launch_bounds__(256) void phase1(const float* __restrict__ Wm1,
                                              const float* __restrict__ Wn,
                                              const float* __restrict__ Wm2,
                                              const float* __restrict__ We,
                                              const float* __restrict__ be,
                                              const float* __restrict__ bm1,
                                              const float* __restrict__ bm2,
                                              const float* __restrict__ Ws,
                                              const float* __restrict__ bs,
                                              __hip_bfloat16* __restrict__ W1pqT,
                                              __hip_bfloat16* __restrict__ W2T,
                                              float* __restrict__ Wc, float* __restrict__ bc,
                                              float* __restrict__ crow,
                                              const float* __restrict__ node_s,
                                              const float* __restrict__ node_v,
                                              const float* __restrict__ Wv,
                                              const float* __restrict__ bv,
                                              __hip_bfloat16* __restrict__ XL2,
                                              const int* __restrict__ ei,
                                              const int* __restrict__ batch,
                                              int* __restrict__ cnt, int* __restrict__ gcnt,
                                              const float* __restrict__ edge_s,
                                              u16* __restrict__ esb) {
    int blk = blockIdx.x, tid = threadIdx.x;
    if (blk < 64) {
        int k = blk;
#pragma unroll
        for (int half = 0; half < 2; ++half) {
            int c = half * 256 + tid;
            int cc = c & 255;
            const float* Wm1h = (c < 256) ? Wm1 : (Wm1 + 256 * 256);
            float v = 0.f;
            if (k < 23) v = dot256(&Ws[k * 256], Wm1h, cc);
            else if (k < 39) { if (c >= 256) v = Wm1[(512 + (k - 23)) * 256 + cc]; }
            else if (k == 39) v = dot256(bs, Wm1h, cc);
            W1pqT[c * KS + k] = f2b(v);
        }
    } else if (blk < 384) {
        int k = blk - 64, c = tid;
        float v = 0.f;
        if (k < 23) v = dot256(&Ws[k * 256], Wn, c);
        else if (k < 39) v = Wn[(256 + (k - 23)) * 256 + c];
        else if (k == 39) v = dot256(bs, Wn, c);
        else if (k < 296) v = dot256(&Wm2[(k - 40) * 256], Wn, c);
        W2T[c * K2 + k] = f2b(v);
    } else if (blk < 403) {
        int b = blk - 384, c = tid;
        if (b < 17) Wc[b * 256 + c] = dot256(&We[b * 256], &Wm1[528 * 256], c);
        else if (b == 17) bc[c] = bm1[c] + dot256(be, &Wm1[528 * 256], c);
        else crow[c] = dot256(bm2, Wn, c);
    } else if (blk < 12903) {
        int w = tid >> 6, lane = tid & 63;
        int n = (blk - 403) * 4 + w;
        if (n < NN) {
            float lv = (lane < 23) ? node_s[(size_t)n * 23 + lane] : 0.f;
            float vv = (lane < 12) ? node_v[(size_t)n * 12 + lane] : 0.f;
            float nvk[12];
#pragma unroll
            for (int k = 0; k < 12; ++k) nvk[k] = __shfl(vv, k, 64);
            float vn = 0.f;
            if (lane < 16) {
                float b0 = bv[lane];
                float vx = b0, vy = b0, vz = b0;
#pragma unroll
                for (int k = 0; k < 4; ++k) {
                    float wv = Wv[k * 16 + lane];
                    vx += nvk[k * 3 + 0] * wv;
                    vy += nvk[k * 3 + 1] * wv;
                    vz += nvk[k * 3 + 2] * wv;
                }
                vn = sqrtf(vx * vx + vy * vy + vz * vz);
            }
            int vsrc = (lane >= 23 && lane < 39) ? (lane - 23) : 0;
            float vbc = __shfl(vn, vsrc, 64);
            float outv;
            if (lane < 23) outv = lv;
            else if (lane < 39) outv = vbc;
            else if (lane == 39) outv = 1.f;
            else outv = 0.f;
            __hip_bfloat16* row = XL2 + (size_t)n * K2;
            row[lane] = f2b(outv);
            if (lane < 24) row[296 + lane] = f2b(0.f);
        }
    } else if (blk < 14662) {
        int b = blk - 12903;
        if (b < 1563) {
            int e = b * 256 + tid;
            if (e < EE) atomicAdd(&cnt[ei[EE + e]], 1);
        } else {
            int n = (b - 1563) * 256 + tid;
            if (n < NN) atomicAdd(&gcnt[batch[n]], 1);
        }
    } else {
        int idx = (blk - 14662) * 256 + tid;
        if (idx < ESN) esb[idx] = ftou16(edge_s[idx]);
    }
}

// ================= CSR build =================
__global__ __launch_bounds__(256) void scan1(const int* __restrict__ cnt, int* __restrict__ rowptr,
                                             int* __restrict__ bsum) {
    int tid = threadIdx.x, i = blockIdx.x * 256 + tid;
    __shared__ int sd[256];
    int v = (i < NN) ? cnt[i] : 0;
    sd[tid] = v;
    __syncthreads();
    for (int off = 1; off < 256; off <<= 1) {
        int t = (tid >= off) ? sd[tid - off] : 0;
        __syncthreads();
        sd[tid] += t;
        __syncthreads();
    }
    if (i < NN) rowptr[i] = sd[tid] - v;
    if (tid == 255) bsum[blockIdx.x] = sd[255];
}
__global__ __launch_bounds__(256) void scan2(int* __restrict__ bsum, const int* __restrict__ gcnt,
                                             float* __restrict__ ginv) {
    int c = threadIdx.x;
    __shared__ int sd[256];
    int v = (c < 196) ? bsum[c] : 0;
    sd[c] = v;
    __syncthreads();
    for (int off = 1; off < 256; off <<= 1) {
        int t = (c >= off) ? sd[c - off] : 0;
        __syncthreads();
        sd[c] += t;
        __syncthreads();
    }
    if (c < 196) bsum[c] = sd[c] - v;
    ginv[c] = 1.f / fmaxf((float)gcnt[c], 1.f);
}
__global__ __launch_bounds__(256) void scan3(const int* __restrict__ cnt, const int* __restrict__ bsum,
                                             int* __restrict__ rowptr, int* __restrict__ cursor) {
    int i = blockIdx.x * 256 + threadIdx.x;
    if (i < NN) {
        int v = rowptr[i] + bsum[blockIdx.x];
        rowptr[i] = v;
        cursor[i] = v;
        if (i == NN - 1) rowptr[NN] = v + cnt[i];
    }
}

// ================= gemm1 (K=64, single K-tile) + fill_csr fused (independent jobs) =================
// blocks [0,1564): gemm1 tile (m = blk>>2, n0 = (blk&3)*128); blocks [1564,3127): fill_csr
__global__ __launch_bounds__(256, 2) void gemm1_fill(const u16* __restrict__ A, const u16* __restrict__ Bt,
                                                     __hip_bfloat16* __restrict__ C,
                                                     const int* __restrict__ ei, int* __restrict__ cursor,
                                                     int* __restrict__ eid) {
    __shared__ __align__(16) u16 At[128 * 64];
    __shared__ __align__(16) u16 Bs[128 * 64];
    int blk = blockIdx.x, tid = threadIdx.x;
    if (blk >= 1564) {
        int e = (blk - 1564) * 256 + tid;
        if (e < EE) {
            int d = ei[EE + e];
            int pos = atomicAdd(&cursor[d], 1);
            eid[pos] = e;
        }
        return;
    }
    long m0 = (long)(blk >> 2) * 128;
    long n0 = (long)(blk & 3) * 128;
    int wid = tid >> 6, lane = tid & 63;
    int wm = wid >> 1, wn = wid & 1;
    int quad = lane >> 4, l16 = lane & 15;
    f32x4 acc[4][4] = {};
    int r0 = tid >> 3;
    int cc = (tid & 7) * 8;
    const u16* Ab = A + (m0 + r0) * K2 + cc;
    const u16* Bb = Bt + (n0 + r0) * KS + cc;
#pragma unroll
    for (int i = 0; i < 4; ++i) {
        int row = r0 + i * 32;
        __builtin_amdgcn_global_load_lds(
            (const __attribute__((address_space(1))) void*)(Ab + (long)(i * 32) * K2),
            (__attribute__((address_space(3))) void*)(&At[row * 64 + cc]), 16, 0, 0);
    }
#pragma unroll
    for (int i = 0; i < 4; ++i) {
        int row = r0 + i * 32;
        __builtin_amdgcn_global_load_lds(
            (const __attribute__((address_space(1))) void*)(Bb + (long)(i * 32) * KS),
            (__attribute__((address_space(3))) void*)(&Bs[row * 64 + cc]), 16, 0, 0);
    }
    __syncthreads();
#pragma unroll
    for (int kk = 0; kk < 64; kk += 32) {
        short8 af[4], bf[4];
#pragma unroll
        for (int mi = 0; mi < 4; ++mi)
            af[mi] = *(const short8*)&At[(wm * 64 + mi * 16 + l16) * 64 + kk + quad * 8];
#pragma unroll
        for (int ni = 0; ni < 4; ++ni)
            bf[ni] = *(const short8*)&Bs[(wn * 64 + ni * 16 + l16) * 64 + kk + quad * 8];
#pragma unroll
        for (int mi = 0; mi < 4; ++mi) {
#pragma unroll
            for (int ni = 0; ni < 4; ++ni)
                acc[mi][ni] = __builtin_amdgcn_mfma_f32_16x16x32_bf16(af[mi], bf[ni], acc[mi][ni], 0, 0, 0);
        }
    }
#pragma unroll
    for (int mi = 0; mi < 4; ++mi) {
#pragma unroll
        for (int ni = 0; ni < 4; ++ni) {
            long row = m0 + wm * 64 + mi * 16 + quad * 4;
            long col = n0 + wn * 64 + ni * 16 + l16;
#pragma unroll
            for (int r = 0; r < 4; ++r)
                C[(row + r) * 512 + col] = f2b(acc[mi][ni][r]);
        }
    }
}

// ================= edge aggregation: 1-wave blocks, readlane chain, bf16 es ==============
// hidden_e = relu(P[dst]+bc + Q[src] + es[e]@Wc); meanH -> XL2 cols [40,296).
__global__ __launch_bounds__(64, 1) void edge_agg(const u16* __restrict__ PQ,
                                                  const u16* __restrict__ esb,
                                                  const int* __restrict__ ei, const int* __restrict__ eid,
                                                  const int* __restrict__ rowptr, const float* __restrict__ Wc,
                                                  const float* __restrict__ bc, __hip_bfloat16* __restrict__ XL2) {
    int lane = threadIdx.x;
    int n = blockIdx.x;
    int start = rowptr[n], deg = rowptr[n + 1] - start;
    f32x4 wc4[17];
#pragma unroll
    for (int k = 0; k < 17; ++k) wc4[k] = *(const f32x4*)&Wc[k * 256 + lane * 4];
    f32x4 bc4 = *(const f32x4*)&bc[lane * 4];
    short4v p4 = *(const short4v*)&PQ[(size_t)n * 512 + lane * 4];
    f32x4 pb;
#pragma unroll
    for (int i = 0; i < 4; ++i) pb[i] = u16tof((u16)p4[i]) + bc4[i];
    f32x4 acc = {0.f, 0.f, 0.f, 0.f};
    for (int base = 0; base < deg; base += 64) {
        int m = deg - base;
        if (m > 64) m = 64;
        int ee = 0, ss = 0;
        if (lane < m) {
            ee = eid[start + base + lane];
            ss = ei[ee];
        }
        int e0 = __builtin_amdgcn_readlane(ee, 0);
        int s0 = __builtin_amdgcn_readlane(ss, 0);
        short4v q0 = *(const short4v*)&PQ[(size_t)s0 * 512 + 256 + lane * 4];
        float es0 = (lane < 17) ? u16tof(esb[(size_t)e0 * 17 + lane]) : 0.f;
        for (int jj = 0; jj < m; ++jj) {
            short4v q1 = q0;
            float es1 = es0;
            if (jj + 1 < m) {   // wave-uniform
                int e1 = __builtin_amdgcn_readlane(ee, jj + 1);
                int s1 = __builtin_amdgcn_readlane(ss, jj + 1);
                q1 = *(const short4v*)&PQ[(size_t)s1 * 512 + 256 + lane * 4];
                es1 = (lane < 17) ? u16tof(esb[(size_t)e1 * 17 + lane]) : 0.f;
            }
            f32x4 ra = {0.f, 0.f, 0.f, 0.f};
            f32x4 rb = {0.f, 0.f, 0.f, 0.f};
#pragma unroll
            for (int k = 0; k < 8; ++k) ra += wc4[k] * rlf(es0, k);
#pragma unroll
            for (int k = 8; k < 17; ++k) rb += wc4[k] * rlf(es0, k);
#pragma unroll
            for (int i = 0; i < 4; ++i)
                acc[i] += fmaxf(pb[i] + u16tof((u16)q0[i]) + ra[i] + rb[i], 0.f);
            q0 = q1;
            es0 = es1;
        }
    }
    float inv = 1.f / fmaxf((float)deg, 1.f);
    short4v ov;
#pragma unroll
    for (int i = 0; i < 4; ++i) ov[i] = (short)ftou16(acc[i] * inv);
    *(short4v*)&XL2[(size_t)n * K2 + 40 + lane * 4] = ov;
}

// ================= gemm2 + LayerNorm + ReLU + pool, fully fused =================
__global__ __launch_bounds__(256, 2) void gemm2_lnp(const u16* __restrict__ A, const u16* __restrict__ Bt,
                                                    const int* __restrict__ cnt, const int* __restrict__ batch,
                                                    const float* __restrict__ bn, const float* __restrict__ crow,
                                                    const float* __restrict__ gamma, const float* __restrict__ beta,
                                                    const float* __restrict__ ginv, float* __restrict__ out) {
    __shared__ __align__(16) u16 At[64 * 64];
    __shared__ __align__(16) u16 Bs[256 * 64];
    __shared__ float rsum[4][64], rsum2[4][64];
    __shared__ int sdeg[64], sbatch[64];
    int tid = threadIdx.x;
    long m0 = (long)blockIdx.x * 64;
    int w = tid >> 6, lane = tid & 63;
    int quad = lane >> 4, l16 = lane & 15;
    f32x4 acc[4][4] = {};
    int r0 = tid >> 3;
    int cc = (tid & 7) * 8;
    const u16* Ab = A + (m0 + r0) * K2 + cc;
    const u16* Bb = Bt + (long)r0 * K2 + cc;
    for (int kt = 0; kt < K2; kt += 64) {
#pragma unroll
        for (int i = 0; i < 2; ++i) {
            int row = r0 + i * 32;
            __builtin_amdgcn_global_load_lds(
                (const __attribute__((address_space(1))) void*)(Ab + (long)(i * 32) * K2 + kt),
                (__attribute__((address_space(3))) void*)(&At[row * 64 + cc]), 16, 0, 0);
        }
#pragma unroll
        for (int i = 0; i < 8; ++i) {
            int row = r0 + i * 32;
            __builtin_amdgcn_global_load_lds(
                (const __attribute__((address_space(1))) void*)(Bb + (long)(i * 32) * K2 + kt),
                (__attribute__((address_space(3))) void*)(&Bs[row * 64 + cc]), 16, 0, 0);
        }
        __syncthreads();
#pragma unroll
        for (int kk = 0; kk < 64; kk += 32) {
            short8 af[4], bf[4];
#pragma unroll
            for (int mi = 0; mi < 4; ++mi)
                af[mi] = *(const short8*)&At[(mi * 16 + l16) * 64 + kk + quad * 8];
#pragma unroll
            for (int ni = 0; ni < 4; ++ni)
                bf[ni] = *(const short8*)&Bs[(w * 64 + ni * 16 + l16) * 64 + kk + quad * 8];
#pragma unroll
            for (int mi = 0; mi < 4; ++mi) {
#pragma unroll
                for (int ni = 0; ni < 4; ++ni)
                    acc[mi][ni] = __builtin_amdgcn_mfma_f32_16x16x32_bf16(af[mi], bf[ni], acc[mi][ni], 0, 0, 0);
            }
        }
        __syncthreads();
    }
    if (tid < 64) {
        long n = m0 + tid;
        sdeg[tid] = (n < NN) ? cnt[n] : 0;
        sbatch[tid] = (n < NN) ? batch[n] : -1;
    }
    __syncthreads();
    float bn_l[4], cr_l[4], g_l[4], be_l[4];
#pragma unroll
    for (int ni = 0; ni < 4; ++ni) {
        int col = w * 64 + ni * 16 + l16;
        bn_l[ni] = bn[col];
        cr_l[ni] = crow[col];
        g_l[ni] = gamma[col];
        be_l[ni] = beta[col];
    }
#pragma unroll
    for (int mi = 0; mi < 4; ++mi) {
#pragma unroll
        for (int r = 0; r < 4; ++r) {
            int row = mi * 16 + quad * 4 + r;
            float cr_on = (sdeg[row] > 0) ? 1.f : 0.f;
            float s = 0.f, s2 = 0.f;
#pragma unroll
            for (int ni = 0; ni < 4; ++ni) {
                float xv = acc[mi][ni][r] + bn_l[ni] + cr_on * cr_l[ni];
                acc[mi][ni][r] = xv;
                s += xv;
                s2 += xv * xv;
            }
            s += __shfl_xor(s, 1, 64);  s2 += __shfl_xor(s2, 1, 64);
            s += __shfl_xor(s, 2, 64);  s2 += __shfl_xor(s2, 2, 64);
            s += __shfl_xor(s, 4, 64);  s2 += __shfl_xor(s2, 4, 64);
            s += __shfl_xor(s, 8, 64);  s2 += __shfl_xor(s2, 8, 64);
            if (l16 == 0) { rsum[w][row] = s; rsum2[w][row] = s2; }
        }
    }
    __syncthreads();
    float mu_a[4][4], rs_a[4][4];
#pragma unroll
    for (int mi = 0; mi < 4; ++mi) {
#pragma unroll
        for (int r = 0; r < 4; ++r) {
            int row = mi * 16 + quad * 4 + r;
            float S = rsum[0][row] + rsum[1][row] + rsum[2][row] + rsum[3][row];
            float S2 = rsum2[0][row] + rsum2[1][row] + rsum2[2][row] + rsum2[3][row];
            float mu = S * (1.f / 256.f);
            mu_a[mi][r] = mu;
            rs_a[mi][r] = rsqrtf(S2 * (1.f / 256.f) - mu * mu + 1e-5f);
        }
    }
#pragma unroll
    for (int ni = 0; ni < 4; ++ni) {
        int col = w * 64 + ni * 16 + l16;
        float pacc = 0.f;
        int curg = -1;
#pragma unroll
        for (int mi = 0; mi < 4; ++mi) {
#pragma unroll
            for (int r = 0; r < 4; ++r) {
                int row = mi * 16 + quad * 4 + r;
                int g = sbatch[row];
                float y = (acc[mi][ni][r] - mu_a[mi][r]) * rs_a[mi][r] * g_l[ni] + be_l[ni];
                y = fmaxf(y, 0.f);
                if (g != curg) {
                    if (curg >= 0) atomicAdd(&out[curg * 256 + col], pacc * ginv[curg]);
                    pacc = 0.f;
                    curg = g;
                }
                if (g >= 0) pacc += y;
            }
        }
        if (curg >= 0) atomicAdd(&out[curg * 256 + col], pacc * ginv[curg]);
    }
}

extern "C" void kernel_launch(void* const* d_in, const int* in_sizes, int n_in,
                              void* d_out, int out_size, void* d_ws, size_t ws_size,
                              hipStream_t stream) {
    const float* node_s = (const float*)d_in[0];
    const float* node_v = (const float*)d_in[1];
    const float* edge_s = (const float*)d_in[2];
    const int* ei = (const int*)d_in[3];
    const int* batch = (const int*)d_in[4];
    const float* Ws = (const float*)d_in[5];
    const float* bs = (const float*)d_in[6];
    const float* Wv = (const float*)d_in[7];
    const float* bv = (const float*)d_in[8];
    const float* We = (const float*)d_in[9];
    const float* be = (const float*)d_in[10];
    const float* Wm1 = (const float*)d_in[11];
    const float* bm1 = (const float*)d_in[12];
    const float* Wm2 = (const float*)d_in[13];
    const float* bm2 = (const float*)d_in[14];
    const float* Wn = (const float*)d_in[15];
    const float* bn = (const float*)d_in[16];
    const float* gamma = (const float*)d_in[17];
    const float* beta = (const float*)d_in[18];

    char* ws = (char*)d_ws;
    size_t off = 0;
    auto take = [&](size_t n) {
        void* p = ws + off;
        off = (off + n + 255) & ~(size_t)255;
        return p;
    };
    __hip_bfloat16* XL2 = (__hip_bfloat16*)take((size_t)MP * K2 * 2);
    __hip_bfloat16* PQ = (__hip_bfloat16*)take((size_t)MP * 512 * 2);
    __hip_bfloat16* W1pqT = (__hip_bfloat16*)take(512 * KS * 2);
    __hip_bfloat16* W2T = (__hip_bfloat16*)take(256 * K2 * 2);
    float* Wc = (float*)take(17 * 256 * 4);
    float* bc = (float*)take(256 * 4);
    float* crow = (float*)take(256 * 4);
    int* cnt = (int*)take((NN + GG) * 4);
    int* gcnt = cnt + NN;
    float* ginv = (float*)take(GG * 4);
    int* rowptr = (int*)take((NN + 1) * 4);
    int* cursor = (int*)take(NN * 4);
    int* eid = (int*)take(EE * 4);
    u16* esb = (u16*)take((size_t)ESN * 2);   // 13.6 MB bf16 edge_s
    int* bsum = (int*)take(256 * 4);

    hipMemsetAsync(cnt, 0, (NN + GG) * 4, stream);
    hipMemsetAsync(d_out, 0, (size_t)out_size * 4, stream);

    phase1<<<41225, 256, 0, stream>>>(Wm1, Wn, Wm2, We, be, bm1, bm2, Ws, bs,
                                      W1pqT, W2T, Wc, bc, crow,
                                      node_s, node_v, Wv, bv, XL2, ei, batch, cnt, gcnt,
                                      edge_s, esb);

    scan1<<<196, 256, 0, stream>>>(cnt, rowptr, bsum);
    scan2<<<1, 256, 0, stream>>>(bsum, gcnt, ginv);
    scan3<<<196, 256, 0, stream>>>(cnt, bsum, rowptr, cursor);

    // fused: gemm1 (PQ = XL2[:, :64] @ W1pqT^T) + fill_csr
    gemm1_fill<<<3127, 256, 0, stream>>>((const u16*)XL2, (const u16*)W1pqT, PQ, ei, cursor, eid);

    edge_agg<<<NN, 64, 0, stream>>>((const u16*)PQ, esb, ei, eid, rowptr, Wc, bc, XL2);

    // fused: h = XL2 @ W2T^T -> LN -> ReLU -> mean-pool into d_out
    gemm2_lnp<<<782, 256, 0, stream>>>((const u16*)XL2, (const u16*)W2T, cnt, batch,
                                       bn, crow, gamma, beta, ginv, (float*)d_out);
}